// Round 1
// baseline (1333.944 us; speedup 1.0000x reference)
//
#include <hip/hip_runtime.h>
#include <stdint.h>

#define BB 2048
#define TT 200
#define DD 64
#define FF 256   // 4*D
#define H1C 256
#define H2C 128
#define H3C 64

typedef __bf16 bf16x8 __attribute__((ext_vector_type(8)));
typedef float floatx16 __attribute__((ext_vector_type(16)));
typedef unsigned short u16;

__device__ inline u16 f2bf(float f) {
    uint32_t u = __builtin_bit_cast(uint32_t, f);
    u += 0x7fffu + ((u >> 16) & 1u);   // RNE
    return (u16)(u >> 16);
}
__device__ inline float bf2f(u16 h) {
    uint32_t u = ((uint32_t)h) << 16;
    return __builtin_bit_cast(float, u);
}

// ---- weight pre-pack: fp32 row-major W[K][N] -> bf16, MFMA-B-fragment order.
// out[((nt*(K/16)+c)*64 + lane)*8 + j] = bf16(W[(16c + (lane>>5)*8 + j)*N + nt*32 + (lane&31)])
template<int K, int N>
__global__ void pack_weights(const float* __restrict__ W, u16* __restrict__ out) {
    int idx = blockIdx.x * 256 + threadIdx.x;
    if (idx >= K * N) return;
    constexpr int NC = K / 16;
    int j    = idx & 7;
    int lane = (idx >> 3) & 63;
    int rest = idx >> 9;
    int c  = rest % NC;
    int nt = rest / NC;
    int k = c * 16 + ((lane >> 5) << 3) + j;
    int n = nt * 32 + (lane & 31);
    out[idx] = f2bf(W[k * N + n]);
}

// One layer's worth of MFMA tiles for one wave.
// X: LDS bf16 input [64][IN_STRIDE]; Y: LDS bf16 output [64][OUT_STRIDE]
// A-frags for m-tile `mt` held in registers across NTILES n-tiles starting at nt0.
template<int K, int NTOT, int IN_STRIDE, int OUT_STRIDE, int NTILES>
__device__ inline void layer(const u16* X, u16* Y,
                             const u16* __restrict__ Wp,
                             const float* __restrict__ bias,
                             const float* __restrict__ alpha,
                             int mt, int nt0, int lane, int t0) {
    constexpr int NC = K / 16;
    const int m  = lane & 31;
    const int kq = (lane >> 5) << 3;
    const u16* abase = X + (mt * 32 + m) * IN_STRIDE + kq;
    bf16x8 a[NC];
#pragma unroll
    for (int c = 0; c < NC; ++c)
        a[c] = *reinterpret_cast<const bf16x8*>(abase + c * 16);

#pragma unroll
    for (int ntl = 0; ntl < NTILES; ++ntl) {
        const int nt = nt0 + ntl;
        const u16* wb = Wp + (size_t)(nt * NC) * 512 + lane * 8;
        floatx16 acc0, acc1;
#pragma unroll
        for (int i = 0; i < 16; ++i) { acc0[i] = 0.f; acc1[i] = 0.f; }
#pragma unroll
        for (int c = 0; c < NC; c += 2) {
            bf16x8 b0 = *reinterpret_cast<const bf16x8*>(wb + (size_t)c * 512);
            acc0 = __builtin_amdgcn_mfma_f32_32x32x16_bf16(a[c], b0, acc0, 0, 0, 0);
            bf16x8 b1 = *reinterpret_cast<const bf16x8*>(wb + (size_t)(c + 1) * 512);
            acc1 = __builtin_amdgcn_mfma_f32_32x32x16_bf16(a[c + 1], b1, acc1, 0, 0, 0);
        }
        const int n  = nt * 32 + m;
        const float bv = bias[n];
        const int rbase = mt * 32 + ((lane >> 5) << 2);
#pragma unroll
        for (int reg = 0; reg < 16; ++reg) {
            const int row = (reg & 3) + ((reg >> 2) << 3) + rbase;
            const int t = t0 + row;
            float v = acc0[reg] + acc1[reg] + bv;
            if (t < TT) {
                const float al = alpha[t * NTOT + n];
                v = v > 0.f ? v : al * v;      // PReLU
            } else {
                v = 0.f;                        // padded rows
            }
            Y[row * OUT_STRIDE + n] = f2bf(v);
        }
    }
}

__global__ __launch_bounds__(256, 2)
void attn_pool_kernel(const float* __restrict__ Q, const float* __restrict__ Kin,
                      const u16* __restrict__ W1p, const float* __restrict__ b1,
                      const float* __restrict__ a1,
                      const u16* __restrict__ W2p, const float* __restrict__ b2,
                      const float* __restrict__ a2,
                      const u16* __restrict__ W3p, const float* __restrict__ b3,
                      const float* __restrict__ a3,
                      const float* __restrict__ Wl, const float* __restrict__ bl,
                      float* __restrict__ Out) {
    // LDS: smemA holds att_in (stride 264), later reused for h2 (stride 136) + h3 (stride 72).
    // smemB holds h1 (stride 264). Total ~77 KB -> 2 blocks/CU.
    __shared__ __align__(16) u16 smemA[64 * 264];
    __shared__ __align__(16) u16 smemB[64 * 264];
    __shared__ __align__(16) u16 k_sh[64 * 72];
    __shared__ float q_sh[64];
    __shared__ float k0_sh[64];
    __shared__ float score_sh[64];
    __shared__ float pool_red[4][64];

    const int tid  = threadIdx.x;
    const int lane = tid & 63;
    const int w    = tid >> 6;
    const int b    = blockIdx.x;

    if (tid < 16) {
        reinterpret_cast<float4*>(q_sh)[tid] =
            reinterpret_cast<const float4*>(Q + (size_t)b * DD)[tid];
    }
    __syncthreads();

    float pacc = 0.f;   // pooling partial: d = lane, m-quarter = w

    for (int mb = 0; mb < 4; ++mb) {
        const int t0 = mb * 64;

        // ---- stage k row + build att_in = [q, k, q-k, q*k] in bf16
        {
            const int r  = tid >> 2;
            const int c0 = (tid & 3) << 4;
            const int t  = t0 + r;
            u16* attrow = smemA + r * 264;
            u16* krow   = k_sh + r * 72;
            if (t < TT) {
                const float* kp = Kin + ((size_t)b * TT + t) * DD + c0;
#pragma unroll
                for (int i = 0; i < 4; ++i) {
                    const float4 kv = *reinterpret_cast<const float4*>(kp + i * 4);
                    const float4 qv = *reinterpret_cast<const float4*>(&q_sh[c0 + i * 4]);
                    ushort4 uq, uk, ud, up;
                    uq.x = f2bf(qv.x); uq.y = f2bf(qv.y); uq.z = f2bf(qv.z); uq.w = f2bf(qv.w);
                    uk.x = f2bf(kv.x); uk.y = f2bf(kv.y); uk.z = f2bf(kv.z); uk.w = f2bf(kv.w);
                    ud.x = f2bf(qv.x - kv.x); ud.y = f2bf(qv.y - kv.y);
                    ud.z = f2bf(qv.z - kv.z); ud.w = f2bf(qv.w - kv.w);
                    up.x = f2bf(qv.x * kv.x); up.y = f2bf(qv.y * kv.y);
                    up.z = f2bf(qv.z * kv.z); up.w = f2bf(qv.w * kv.w);
                    const int cc = c0 + i * 4;
                    *reinterpret_cast<ushort4*>(&attrow[cc])       = uq;
                    *reinterpret_cast<ushort4*>(&attrow[64 + cc])  = uk;
                    *reinterpret_cast<ushort4*>(&attrow[128 + cc]) = ud;
                    *reinterpret_cast<ushort4*>(&attrow[192 + cc]) = up;
                    *reinterpret_cast<ushort4*>(&krow[cc])         = uk;
                    if (cc == 0) k0_sh[r] = kv.x;   // exact fp32 for mask
                }
            } else {
                const ushort4 z = {0, 0, 0, 0};
#pragma unroll
                for (int i = 0; i < 4; ++i) {
                    const int cc = c0 + i * 4;
                    *reinterpret_cast<ushort4*>(&attrow[cc])       = z;
                    *reinterpret_cast<ushort4*>(&attrow[64 + cc])  = z;
                    *reinterpret_cast<ushort4*>(&attrow[128 + cc]) = z;
                    *reinterpret_cast<ushort4*>(&attrow[192 + cc]) = z;
                    *reinterpret_cast<ushort4*>(&krow[cc])         = z;
                }
                if (c0 == 0) k0_sh[r] = 0.f;
            }
        }
        __syncthreads();

        // ---- layer1: att[64,256] @ W1[256,256] -> h1 (smemB)
#pragma unroll
        for (int mt = 0; mt < 2; ++mt)
            layer<FF, H1C, 264, 264, 2>(smemA, smemB, W1p, b1, a1, mt, w * 2, lane, t0);
        __syncthreads();

        // ---- layer2: h1[64,256] @ W2[256,128] -> h2 (smemA, stride 136)
#pragma unroll
        for (int mt = 0; mt < 2; ++mt)
            layer<H1C, H2C, 264, 136, 1>(smemB, smemA, W2p, b2, a2, mt, w, lane, t0);
        __syncthreads();

        // ---- layer3: h2[64,128] @ W3[128,64] -> h3 (smemA + 64*136, stride 72)
        layer<H2C, H3C, 136, 72, 1>(smemA, smemA + 64 * 136, W3p, b3, a3,
                                    w >> 1, w & 1, lane, t0);
        __syncthreads();

        // ---- score = h3 @ Wl + bl, masked
        {
            const int m = tid >> 2;
            const int p = tid & 3;
            const u16* hrow = smemA + 64 * 136 + m * 72 + p * 16;
            const float* wl = Wl + p * 16;
            float s = 0.f;
#pragma unroll
            for (int i = 0; i < 16; ++i) s += bf2f(hrow[i]) * wl[i];
            s += __shfl_xor(s, 1);
            s += __shfl_xor(s, 2);
            if (p == 0) {
                const int t = t0 + m;
                float sc = s + bl[0];
                if (t >= TT || k0_sh[m] == 0.f) sc = 0.f;
                score_sh[m] = sc;
            }
        }
        __syncthreads();

        // ---- pooling partial: out[b,d] += sum_m score[m]*k[m][d]
        {
            const u16* kp = k_sh + w * 16 * 72 + lane;
#pragma unroll
            for (int i = 0; i < 16; ++i)
                pacc += score_sh[w * 16 + i] * bf2f(kp[i * 72]);
        }
        __syncthreads();
    }

    pool_red[w][lane] = pacc;
    __syncthreads();
    if (tid < 64) {
        Out[(size_t)b * DD + tid] =
            pool_red[0][tid] + pool_red[1][tid] + pool_red[2][tid] + pool_red[3][tid];
    }
}

extern "C" void kernel_launch(void* const* d_in, const int* in_sizes, int n_in,
                              void* d_out, int out_size, void* d_ws, size_t ws_size,
                              hipStream_t stream) {
    (void)in_sizes; (void)n_in; (void)out_size; (void)ws_size;
    const float* Q  = (const float*)d_in[0];
    const float* Kk = (const float*)d_in[1];
    const float* W1 = (const float*)d_in[2];
    const float* b1 = (const float*)d_in[3];
    const float* a1 = (const float*)d_in[4];
    const float* W2 = (const float*)d_in[5];
    const float* b2 = (const float*)d_in[6];
    const float* a2 = (const float*)d_in[7];
    const float* W3 = (const float*)d_in[8];
    const float* b3 = (const float*)d_in[9];
    const float* a3 = (const float*)d_in[10];
    const float* Wl = (const float*)d_in[11];
    const float* bl = (const float*)d_in[12];
    float* Out = (float*)d_out;

    u16* ws  = (u16*)d_ws;
    u16* W1p = ws;                       // 65536 bf16
    u16* W2p = ws + 65536;               // 32768 bf16
    u16* W3p = ws + 65536 + 32768;       //  8192 bf16

    hipLaunchKernelGGL((pack_weights<FF, H1C>),  dim3(FF * H1C / 256),  dim3(256), 0, stream, W1, W1p);
    hipLaunchKernelGGL((pack_weights<H1C, H2C>), dim3(H1C * H2C / 256), dim3(256), 0, stream, W2, W2p);
    hipLaunchKernelGGL((pack_weights<H2C, H3C>), dim3(H2C * H3C / 256), dim3(256), 0, stream, W3, W3p);

    hipLaunchKernelGGL(attn_pool_kernel, dim3(BB), dim3(256), 0, stream,
                       Q, Kk, W1p, b1, a1, W2p, b2, a2, W3p, b3, a3, Wl, bl, Out);
}

// Round 2
// 665.990 us; speedup vs baseline: 2.0029x; 2.0029x over previous
//
#include <hip/hip_runtime.h>
#include <stdint.h>

#define BB 2048
#define TT 200
#define DD 64
#define FF 256   // 4*D
#define H1C 256
#define H2C 128
#define H3C 64

typedef __bf16 bf16x8 __attribute__((ext_vector_type(8)));
typedef float floatx16 __attribute__((ext_vector_type(16)));
typedef float f32x4 __attribute__((ext_vector_type(4)));
typedef unsigned short u16;
typedef u16 u16x8 __attribute__((ext_vector_type(8)));

__device__ inline u16 f2bf(float f) {
    uint32_t u = __builtin_bit_cast(uint32_t, f);
    u += 0x7fffu + ((u >> 16) & 1u);   // RNE
    return (u16)(u >> 16);
}
__device__ inline float bf2f(u16 h) {
    uint32_t u = ((uint32_t)h) << 16;
    return __builtin_bit_cast(float, u);
}

// ---- weight pre-pack: fp32 row-major W[K][N] -> bf16, MFMA-B-fragment order.
// out[((nt*(K/16)+c)*64 + lane)*8 + j] = bf16(W[(16c + (lane>>5)*8 + j)*N + nt*32 + (lane&31)])
template<int K, int N>
__global__ void pack_weights(const float* __restrict__ W, u16* __restrict__ out) {
    int idx = blockIdx.x * 256 + threadIdx.x;
    if (idx >= K * N) return;
    constexpr int NC = K / 16;
    int j    = idx & 7;
    int lane = (idx >> 3) & 63;
    int rest = idx >> 9;
    int c  = rest % NC;
    int nt = rest / NC;
    int k = c * 16 + ((lane >> 5) << 3) + j;
    int n = nt * 32 + (lane & 31);
    out[idx] = f2bf(W[k * N + n]);
}

// ---- alpha pre-pack: fp32 alpha[T][N] -> bf16 in MFMA C/D epilogue order.
// out[((mq*NT+nt)*64 + lane)*16 + reg] = alpha[t][n],
//   row = (reg&3) + 8*(reg>>2) + 4*(lane>>5) + 32*(mq&1); t = 64*(mq>>1)+row
//   n = nt*32 + (lane&31); zero for t >= TT (padded rows).
template<int NTOT>
__global__ void pack_alpha(const float* __restrict__ A, u16* __restrict__ out) {
    constexpr int NT = NTOT / 32;
    int idx = blockIdx.x * 256 + threadIdx.x;
    if (idx >= 256 * NTOT) return;
    int reg  = idx & 15;
    int lane = (idx >> 4) & 63;
    int tl   = idx >> 10;
    int nt = tl % NT;
    int mq = tl / NT;                 // 0..7 (global 32-row tile)
    int row = (reg & 3) + ((reg >> 2) << 3) + ((lane >> 5) << 2) + ((mq & 1) << 5);
    int t = ((mq >> 1) << 6) + row;
    int n = nt * 32 + (lane & 31);
    out[idx] = (t < TT) ? f2bf(A[t * NTOT + n]) : (u16)0;
}

// One layer: X[64][IN_S] (LDS bf16) @ Wp -> Y[64][OUT_S] (LDS bf16), PReLU fused.
// Streams A and B fragments (no big register arrays). B-frag reused across MT m-tiles.
template<int K, int NTOT, int IN_S, int OUT_S, int MT>
__device__ inline void layer_g(const u16* X, u16* Y,
                               const u16* __restrict__ Wp,
                               const float* __restrict__ bias,
                               const u16* __restrict__ Ap,
                               int nt, int mt0, int lane, int mb) {
    constexpr int NC = K / 16;
    constexpr int NT = NTOT / 32;
    const int m  = lane & 31;
    const int kq = (lane >> 5) << 3;

    floatx16 acc[MT];
#pragma unroll
    for (int mtl = 0; mtl < MT; ++mtl)
#pragma unroll
        for (int i = 0; i < 16; ++i) acc[mtl][i] = 0.f;

    const u16* wb = Wp + (size_t)(nt * NC) * 512 + lane * 8;
    const u16* ab = X + kq;
#pragma unroll
    for (int c = 0; c < NC; ++c) {
        bf16x8 bfr = *reinterpret_cast<const bf16x8*>(wb + (size_t)c * 512);
#pragma unroll
        for (int mtl = 0; mtl < MT; ++mtl) {
            bf16x8 afr = *reinterpret_cast<const bf16x8*>(
                ab + ((mt0 + mtl) * 32 + m) * IN_S + c * 16);
            acc[mtl] = __builtin_amdgcn_mfma_f32_32x32x16_bf16(afr, bfr, acc[mtl], 0, 0, 0);
        }
    }

    const int n  = nt * 32 + m;
    const float bv = bias[n];
#pragma unroll
    for (int mtl = 0; mtl < MT; ++mtl) {
        const int mt = mt0 + mtl;
        const u16* ap = Ap + (((size_t)((mb * 2 + mt) * NT + nt) * 64 + lane) << 4);
        u16x8 av0 = *reinterpret_cast<const u16x8*>(ap);
        u16x8 av1 = *reinterpret_cast<const u16x8*>(ap + 8);
        const int rbase = mt * 32 + ((lane >> 5) << 2);
#pragma unroll
        for (int reg = 0; reg < 16; ++reg) {
            const int row = (reg & 3) + ((reg >> 2) << 3) + rbase;
            const int t = mb * 64 + row;
            const float al = bf2f(reg < 8 ? av0[reg & 7] : av1[reg & 7]);
            float v = acc[mtl][reg] + bv;
            v = fmaxf(v, 0.f) + al * fminf(v, 0.f);       // PReLU
            v = (t < TT) ? v : 0.f;                        // zero padded rows
            Y[row * OUT_S + n] = f2bf(v);
        }
    }
}

__global__ __launch_bounds__(512, 4)
void attn_pool_kernel(const float* __restrict__ Q, const float* __restrict__ Kin,
                      const u16* __restrict__ W1p, const float* __restrict__ b1,
                      const u16* __restrict__ A1p,
                      const u16* __restrict__ W2p, const float* __restrict__ b2,
                      const u16* __restrict__ A2p,
                      const u16* __restrict__ W3p, const float* __restrict__ b3,
                      const u16* __restrict__ A3p,
                      const float* __restrict__ Wl, const float* __restrict__ bl,
                      float* __restrict__ Out) {
    __shared__ __align__(16) u16 smemA[64 * 264];   // att_in; later h2 (stride 136) + h3 (stride 72)
    __shared__ __align__(16) u16 smemB[64 * 264];   // h1
    __shared__ __align__(16) u16 k_sh[64 * 72];
    __shared__ float q_sh[64];
    __shared__ float k0_sh[64];
    __shared__ float score_sh[64];
    __shared__ float pool_red[8][64];

    const int tid  = threadIdx.x;
    const int lane = tid & 63;
    const int w    = tid >> 6;          // 0..7
    const int b    = blockIdx.x;

    if (tid < 16) {
        reinterpret_cast<f32x4*>(q_sh)[tid] =
            reinterpret_cast<const f32x4*>(Q + (size_t)b * DD)[tid];
    }
    __syncthreads();

    float pacc = 0.f;                   // pooling partial: d = lane, row-group = w

    for (int mb = 0; mb < 4; ++mb) {
        const int t0 = mb * 64;

        // ---- stage k row (nontemporal) + build att_in = [q, k, q-k, q*k] bf16
        {
            const int r  = tid >> 3;            // 0..63
            const int c0 = (tid & 7) << 3;      // 0..56
            const int t  = t0 + r;
            u16* attrow = smemA + r * 264;
            u16* krow   = k_sh + r * 72;
            if (t < TT) {
                const f32x4* kp = reinterpret_cast<const f32x4*>(
                    Kin + ((size_t)b * TT + t) * DD + c0);
#pragma unroll
                for (int i = 0; i < 2; ++i) {
                    const f32x4 kv = __builtin_nontemporal_load(kp + i);
                    const f32x4 qv = *reinterpret_cast<const f32x4*>(&q_sh[c0 + 4 * i]);
                    ushort4 uq, uk, ud, up;
                    uq.x = f2bf(qv[0]); uq.y = f2bf(qv[1]); uq.z = f2bf(qv[2]); uq.w = f2bf(qv[3]);
                    uk.x = f2bf(kv[0]); uk.y = f2bf(kv[1]); uk.z = f2bf(kv[2]); uk.w = f2bf(kv[3]);
                    ud.x = f2bf(qv[0] - kv[0]); ud.y = f2bf(qv[1] - kv[1]);
                    ud.z = f2bf(qv[2] - kv[2]); ud.w = f2bf(qv[3] - kv[3]);
                    up.x = f2bf(qv[0] * kv[0]); up.y = f2bf(qv[1] * kv[1]);
                    up.z = f2bf(qv[2] * kv[2]); up.w = f2bf(qv[3] * kv[3]);
                    const int cc = c0 + i * 4;
                    *reinterpret_cast<ushort4*>(&attrow[cc])       = uq;
                    *reinterpret_cast<ushort4*>(&attrow[64 + cc])  = uk;
                    *reinterpret_cast<ushort4*>(&attrow[128 + cc]) = ud;
                    *reinterpret_cast<ushort4*>(&attrow[192 + cc]) = up;
                    *reinterpret_cast<ushort4*>(&krow[cc])         = uk;
                    if (cc == 0) k0_sh[r] = kv[0];   // exact fp32 for mask
                }
            } else {
                const ushort4 z = {0, 0, 0, 0};
#pragma unroll
                for (int i = 0; i < 2; ++i) {
                    const int cc = c0 + i * 4;
                    *reinterpret_cast<ushort4*>(&attrow[cc])       = z;
                    *reinterpret_cast<ushort4*>(&attrow[64 + cc])  = z;
                    *reinterpret_cast<ushort4*>(&attrow[128 + cc]) = z;
                    *reinterpret_cast<ushort4*>(&attrow[192 + cc]) = z;
                    *reinterpret_cast<ushort4*>(&krow[cc])         = z;
                }
                if (c0 == 0) k0_sh[r] = 0.f;
            }
        }
        __syncthreads();

        // ---- layer1: att[64,256] @ W1[256,256] -> h1 (smemB); wave w -> nt=w, 2 m-tiles
        layer_g<FF, H1C, 264, 264, 2>(smemA, smemB, W1p, b1, A1p, w, 0, lane, mb);
        __syncthreads();

        // ---- layer2: h1[64,256] @ W2[256,128] -> h2 (smemA, stride 136)
        layer_g<H1C, H2C, 264, 136, 1>(smemB, smemA, W2p, b2, A2p, w & 3, w >> 2, lane, mb);
        __syncthreads();

        // ---- layer3: h2[64,128] @ W3[128,64] -> h3 (smemA + 64*136, stride 72); waves 0-3
        if (w < 4)
            layer_g<H2C, H3C, 136, 72, 1>(smemA, smemA + 64 * 136, W3p, b3, A3p,
                                          w & 1, w >> 1, lane, mb);
        __syncthreads();

        // ---- score = h3 @ Wl + bl, masked (512 threads: 64 rows x 8-way split)
        {
            const int m = tid >> 3;
            const int p = tid & 7;
            const u16* hrow = smemA + 64 * 136 + m * 72 + p * 8;
            u16x8 hv = *reinterpret_cast<const u16x8*>(hrow);
            const float* wl = Wl + p * 8;
            float s = 0.f;
#pragma unroll
            for (int i = 0; i < 8; ++i) s += bf2f(hv[i]) * wl[i];
            s += __shfl_xor(s, 1);
            s += __shfl_xor(s, 2);
            s += __shfl_xor(s, 4);
            if (p == 0) {
                const int t = t0 + m;
                float sc = s + bl[0];
                if (t >= TT || k0_sh[m] == 0.f) sc = 0.f;
                score_sh[m] = sc;
            }
        }
        __syncthreads();

        // ---- pooling partial: out[b,d] += sum_m score[m]*k[m][d]; 8 rows per wave
        {
            const u16* kp = k_sh + w * 8 * 72 + lane;
#pragma unroll
            for (int i = 0; i < 8; ++i)
                pacc += score_sh[w * 8 + i] * bf2f(kp[i * 72]);
        }
        __syncthreads();
    }

    pool_red[w][lane] = pacc;
    __syncthreads();
    if (tid < 64) {
        float s = 0.f;
#pragma unroll
        for (int i = 0; i < 8; ++i) s += pool_red[i][tid];
        Out[(size_t)b * DD + tid] = s;
    }
}

extern "C" void kernel_launch(void* const* d_in, const int* in_sizes, int n_in,
                              void* d_out, int out_size, void* d_ws, size_t ws_size,
                              hipStream_t stream) {
    (void)in_sizes; (void)n_in; (void)out_size; (void)ws_size;
    const float* Q  = (const float*)d_in[0];
    const float* Kk = (const float*)d_in[1];
    const float* W1 = (const float*)d_in[2];
    const float* b1 = (const float*)d_in[3];
    const float* a1 = (const float*)d_in[4];
    const float* W2 = (const float*)d_in[5];
    const float* b2 = (const float*)d_in[6];
    const float* a2 = (const float*)d_in[7];
    const float* W3 = (const float*)d_in[8];
    const float* b3 = (const float*)d_in[9];
    const float* a3 = (const float*)d_in[10];
    const float* Wl = (const float*)d_in[11];
    const float* bl = (const float*)d_in[12];
    float* Out = (float*)d_out;

    u16* ws  = (u16*)d_ws;
    u16* W1p = ws;                         // 65536 bf16
    u16* W2p = W1p + 65536;                // 32768
    u16* W3p = W2p + 32768;                //  8192
    u16* A1p = W3p + 8192;                 // 65536
    u16* A2p = A1p + 65536;                // 32768
    u16* A3p = A2p + 32768;                // 16384  (total 442 KB)

    hipLaunchKernelGGL((pack_weights<FF, H1C>),  dim3(FF * H1C / 256),  dim3(256), 0, stream, W1, W1p);
    hipLaunchKernelGGL((pack_weights<H1C, H2C>), dim3(H1C * H2C / 256), dim3(256), 0, stream, W2, W2p);
    hipLaunchKernelGGL((pack_weights<H2C, H3C>), dim3(H2C * H3C / 256), dim3(256), 0, stream, W3, W3p);
    hipLaunchKernelGGL((pack_alpha<H1C>), dim3(256 * H1C / 256), dim3(256), 0, stream, a1, A1p);
    hipLaunchKernelGGL((pack_alpha<H2C>), dim3(256 * H2C / 256), dim3(256), 0, stream, a2, A2p);
    hipLaunchKernelGGL((pack_alpha<H3C>), dim3(256 * H3C / 256), dim3(256), 0, stream, a3, A3p);

    hipLaunchKernelGGL(attn_pool_kernel, dim3(BB), dim3(512), 0, stream,
                       Q, Kk, W1p, b1, A1p, W2p, b2, A2p, W3p, b3, A3p, Wl, bl, Out);
}

// Round 3
// 395.829 us; speedup vs baseline: 3.3700x; 1.6825x over previous
//
#include <hip/hip_runtime.h>
#include <stdint.h>

#define BB 2048
#define TT 200
#define DD 64
#define FF 256   // 4*D
#define H1C 256
#define H2C 128
#define H3C 64

typedef __bf16 bf16x8 __attribute__((ext_vector_type(8)));
typedef float floatx16 __attribute__((ext_vector_type(16)));
typedef float f32x4 __attribute__((ext_vector_type(4)));
typedef uint32_t u32x4 __attribute__((ext_vector_type(4)));
typedef unsigned short u16;
typedef u16 u16x8 __attribute__((ext_vector_type(8)));

__device__ inline u16 f2bf(float f) {
    uint32_t u = __builtin_bit_cast(uint32_t, f) + 0x8000u;  // round-half-away
    return (u16)(u >> 16);
}
__device__ inline float bf2f(u16 h) {
    uint32_t u = ((uint32_t)h) << 16;
    return __builtin_bit_cast(float, u);
}
// pack two floats -> bf16x2 (lo in low half) with 2 adds + 1 v_perm_b32
__device__ inline uint32_t pkbf(float lo, float hi) {
    uint32_t ul = __builtin_bit_cast(uint32_t, lo) + 0x8000u;
    uint32_t uh = __builtin_bit_cast(uint32_t, hi) + 0x8000u;
    return __builtin_amdgcn_perm(uh, ul, 0x07060302);
}

// ---- packing (device helpers fused into one launch) ----
// W[K][N] fp32 row-major -> bf16 MFMA-B-fragment order
template<int K, int N>
__device__ inline void pack_w_dev(const float* __restrict__ W, u16* __restrict__ out, int blk) {
    constexpr int NC = K / 16;
    int idx = blk * 256 + threadIdx.x;
    int j    = idx & 7;
    int lane = (idx >> 3) & 63;
    int rest = idx >> 9;
    int c  = rest % NC;
    int nt = rest / NC;
    int k = c * 16 + ((lane >> 5) << 3) + j;
    int n = nt * 32 + (lane & 31);
    out[idx] = f2bf(W[k * N + n]);
}
// alpha[T][N] fp32 -> bf16 in MFMA C/D epilogue order (zero for t>=TT)
template<int NTOT>
__device__ inline void pack_a_dev(const float* __restrict__ A, u16* __restrict__ out, int blk) {
    constexpr int NT = NTOT / 32;
    int idx = blk * 256 + threadIdx.x;
    int reg  = idx & 15;
    int lane = (idx >> 4) & 63;
    int tl   = idx >> 10;
    int nt = tl % NT;
    int mq = tl / NT;
    int row = (reg & 3) + ((reg >> 2) << 3) + ((lane >> 5) << 2) + ((mq & 1) << 5);
    int t = ((mq >> 1) << 6) + row;
    int n = nt * 32 + (lane & 31);
    out[idx] = (t < TT) ? f2bf(A[t * NTOT + n]) : (u16)0;
}

__global__ void pack_all(const float* __restrict__ W1, const float* __restrict__ W2,
                         const float* __restrict__ W3, const float* __restrict__ a1,
                         const float* __restrict__ a2, const float* __restrict__ a3,
                         u16* W1p, u16* W2p, u16* W3p, u16* A1p, u16* A2p, u16* A3p) {
    int blk = blockIdx.x;
    if      (blk < 256) pack_w_dev<FF, H1C>(W1, W1p, blk);
    else if (blk < 384) pack_w_dev<H1C, H2C>(W2, W2p, blk - 256);
    else if (blk < 416) pack_w_dev<H2C, H3C>(W3, W3p, blk - 384);
    else if (blk < 672) pack_a_dev<H1C>(a1, A1p, blk - 416);
    else if (blk < 800) pack_a_dev<H2C>(a2, A2p, blk - 672);
    else                pack_a_dev<H3C>(a3, A3p, blk - 800);
}

// One layer, B-fragments resident in registers. LDS->MFMA->LDS only.
template<int K, int NTOT, int IN_S, int OUT_S, int MT>
__device__ __attribute__((always_inline)) inline
void layer_r(const u16* X, u16* Y, const bf16x8 (&wf)[K / 16],
             const float* __restrict__ bias, const u16* __restrict__ Ap,
             int nt, int mt0, int lane, int mb) {
    constexpr int NC = K / 16;
    constexpr int NT = NTOT / 32;
    const int m  = lane & 31;
    const int kq = (lane >> 5) << 3;
    const int n  = nt * 32 + m;

    // prefetch alpha (global, L2-resident) before the MFMA chain
    u16x8 av[MT][2];
#pragma unroll
    for (int mtl = 0; mtl < MT; ++mtl) {
        const u16* ap = Ap + (((size_t)((mb * 2 + mt0 + mtl) * NT + nt) * 64 + lane) << 4);
        av[mtl][0] = *reinterpret_cast<const u16x8*>(ap);
        av[mtl][1] = *reinterpret_cast<const u16x8*>(ap + 8);
    }
    const float bv = bias[n];

    floatx16 acc[MT];
#pragma unroll
    for (int mtl = 0; mtl < MT; ++mtl)
#pragma unroll
        for (int i = 0; i < 16; ++i) acc[mtl][i] = bv;   // bias pre-added

#pragma unroll
    for (int c = 0; c < NC; ++c) {
#pragma unroll
        for (int mtl = 0; mtl < MT; ++mtl) {
            bf16x8 afr = *reinterpret_cast<const bf16x8*>(
                X + ((mt0 + mtl) * 32 + m) * IN_S + c * 16 + kq);
            acc[mtl] = __builtin_amdgcn_mfma_f32_32x32x16_bf16(afr, wf[c], acc[mtl], 0, 0, 0);
        }
    }

#pragma unroll
    for (int mtl = 0; mtl < MT; ++mtl) {
        const int rbase = (mt0 + mtl) * 32 + ((lane >> 5) << 2);
#pragma unroll
        for (int reg = 0; reg < 16; ++reg) {
            const int row = (reg & 3) + ((reg >> 2) << 3) + rbase;
            float v = acc[mtl][reg];
            const float al = bf2f(reg < 8 ? av[mtl][0][reg & 7] : av[mtl][1][reg & 7]);
            v = fmaxf(v, 0.f) + al * fminf(v, 0.f);      // PReLU (no pad-zeroing: masked later)
            Y[row * OUT_S + n] = f2bf(v);
        }
    }
}

__device__ inline void load_k(const float* __restrict__ Kin, int b, int t, int c0,
                              f32x4& a, f32x4& c) {
    if (t < TT) {
        const f32x4* p = reinterpret_cast<const f32x4*>(Kin + ((size_t)b * TT + t) * DD + c0);
        a = __builtin_nontemporal_load(p);
        c = __builtin_nontemporal_load(p + 1);
    } else {
        a = f32x4{0.f, 0.f, 0.f, 0.f};
        c = f32x4{0.f, 0.f, 0.f, 0.f};
    }
}

__global__ __launch_bounds__(512, 2)
void attn_pool_kernel(const float* __restrict__ Q, const float* __restrict__ Kin,
                      const u16* __restrict__ W1p, const float* __restrict__ b1,
                      const u16* __restrict__ A1p,
                      const u16* __restrict__ W2p, const float* __restrict__ b2,
                      const u16* __restrict__ A2p,
                      const u16* __restrict__ W3p, const float* __restrict__ b3,
                      const u16* __restrict__ A3p,
                      const float* __restrict__ Wl, const float* __restrict__ bl,
                      float* __restrict__ Out) {
    __shared__ __align__(16) u16 att[64 * 264];     // att_in; later h2 (stride 136) + h3 (stride 72)
    __shared__ __align__(16) u16 h1s[64 * 264];
    __shared__ __align__(16) u16 k_sh[2][64 * 72];  // double-buffered
    __shared__ float q_sh[64];
    __shared__ float k0_sh[64];
    __shared__ float score_sh[64];
    __shared__ float pool_red[8][64];

    const int tid  = threadIdx.x;
    const int lane = tid & 63;
    const int w    = tid >> 6;          // 0..7
    const int b    = blockIdx.x;
    const int r    = tid >> 3;          // staging row 0..63
    const int c0   = (tid & 7) << 3;    // staging col group

    // ---- persistent B-fragments in registers (once per block) ----
    bf16x8 w1f[16], w2f[16], w3f[8];
    {
        const u16* p1 = W1p + ((size_t)(w * 16) * 64 + lane) * 8;
#pragma unroll
        for (int c = 0; c < 16; ++c)
            w1f[c] = *reinterpret_cast<const bf16x8*>(p1 + (size_t)c * 512);
        const u16* p2 = W2p + ((size_t)((w & 3) * 16) * 64 + lane) * 8;
#pragma unroll
        for (int c = 0; c < 16; ++c)
            w2f[c] = *reinterpret_cast<const bf16x8*>(p2 + (size_t)c * 512);
        const u16* p3 = W3p + ((size_t)((w & 1) * 8) * 64 + lane) * 8;
#pragma unroll
        for (int c = 0; c < 8; ++c)
            w3f[c] = *reinterpret_cast<const bf16x8*>(p3 + (size_t)c * 512);
    }

    if (tid < 16) {
        reinterpret_cast<f32x4*>(q_sh)[tid] =
            reinterpret_cast<const f32x4*>(Q + (size_t)b * DD)[tid];
    }

    f32x4 kc0, kc1, kn0, kn1;
    load_k(Kin, b, r, c0, kc0, kc1);    // mb=0 rows
    __syncthreads();                    // q_sh ready

    float pacc = 0.f;

#pragma unroll 1
    for (int mb = 0; mb < 4; ++mb) {
        const int buf = mb & 1;
        const int t0  = mb * 64;

        // prefetch next mb's k (latency hidden behind this mb's compute)
        if (mb < 3) load_k(Kin, b, t0 + 64 + r, c0, kn0, kn1);

        // ---- stage att_in = [q | k | q-k | q*k] (bf16) + k_sh from registers
        {
            u16* attrow = att + r * 264;
            const f32x4 q0 = *reinterpret_cast<const f32x4*>(&q_sh[c0]);
            const f32x4 q1 = *reinterpret_cast<const f32x4*>(&q_sh[c0 + 4]);
            u32x4 uq = { pkbf(q0[0], q0[1]), pkbf(q0[2], q0[3]),
                         pkbf(q1[0], q1[1]), pkbf(q1[2], q1[3]) };
            u32x4 uk = { pkbf(kc0[0], kc0[1]), pkbf(kc0[2], kc0[3]),
                         pkbf(kc1[0], kc1[1]), pkbf(kc1[2], kc1[3]) };
            u32x4 ud = { pkbf(q0[0] - kc0[0], q0[1] - kc0[1]),
                         pkbf(q0[2] - kc0[2], q0[3] - kc0[3]),
                         pkbf(q1[0] - kc1[0], q1[1] - kc1[1]),
                         pkbf(q1[2] - kc1[2], q1[3] - kc1[3]) };
            u32x4 up = { pkbf(q0[0] * kc0[0], q0[1] * kc0[1]),
                         pkbf(q0[2] * kc0[2], q0[3] * kc0[3]),
                         pkbf(q1[0] * kc1[0], q1[1] * kc1[1]),
                         pkbf(q1[2] * kc1[2], q1[3] * kc1[3]) };
            *reinterpret_cast<u32x4*>(attrow + c0)       = uq;
            *reinterpret_cast<u32x4*>(attrow + 64 + c0)  = uk;
            *reinterpret_cast<u32x4*>(attrow + 128 + c0) = ud;
            *reinterpret_cast<u32x4*>(attrow + 192 + c0) = up;
            *reinterpret_cast<u32x4*>(k_sh[buf] + r * 72 + c0) = uk;
            if (c0 == 0) k0_sh[r] = kc0[0];
        }
        __syncthreads();                                            // (1) att ready

        // ---- layer1: att[64,256] @ W1 -> h1; wave w owns nt=w, 2 m-tiles
        layer_r<FF, H1C, 264, 264, 2>(att, h1s, w1f, b1, A1p, w, 0, lane, mb);
        __syncthreads();                                            // (2) h1 ready

        // ---- layer2: h1 @ W2 -> h2 (att region, stride 136)
        layer_r<H1C, H2C, 264, 136, 1>(h1s, att, w2f, b2, A2p, w & 3, w >> 2, lane, mb);
        __syncthreads();                                            // (3) h2 ready

        // ---- layer3: h2 @ W3 -> h3 (att + 64*136, stride 72); waves 0-3
        if (w < 4)
            layer_r<H2C, H3C, 136, 72, 1>(att, att + 64 * 136, w3f, b3, A3p,
                                          w & 1, w >> 1, lane, mb);
        __syncthreads();                                            // (4) h3 ready

        // ---- score = h3 @ Wl + bl, masked
        {
            const int sm = tid >> 3;
            const int p  = tid & 7;
            const u16* hrow = att + 64 * 136 + sm * 72 + p * 8;
            u16x8 hv = *reinterpret_cast<const u16x8*>(hrow);
            const f32x4 wl0 = *reinterpret_cast<const f32x4*>(Wl + p * 8);
            const f32x4 wl1 = *reinterpret_cast<const f32x4*>(Wl + p * 8 + 4);
            float s = 0.f;
#pragma unroll
            for (int i = 0; i < 4; ++i) s += bf2f(hv[i]) * wl0[i];
#pragma unroll
            for (int i = 0; i < 4; ++i) s += bf2f(hv[4 + i]) * wl1[i];
            s += __shfl_xor(s, 1);
            s += __shfl_xor(s, 2);
            s += __shfl_xor(s, 4);
            if (p == 0) {
                const int t = t0 + sm;
                float sc = s + bl[0];
                if (t >= TT || k0_sh[sm] == 0.f) sc = 0.f;
                score_sh[sm] = sc;
            }
        }
        __syncthreads();                                            // (5) scores ready

        // ---- pooling partial (overlaps next iteration's staging; k_sh double-buffered)
        {
            const u16* kp = k_sh[buf] + (w * 8) * 72 + lane;
#pragma unroll
            for (int i = 0; i < 8; ++i)
                pacc += score_sh[w * 8 + i] * bf2f(kp[i * 72]);
        }
        kc0 = kn0; kc1 = kn1;
    }

    pool_red[w][lane] = pacc;
    __syncthreads();
    if (tid < 64) {
        float s = 0.f;
#pragma unroll
        for (int i = 0; i < 8; ++i) s += pool_red[i][tid];
        Out[(size_t)b * DD + tid] = s;
    }
}

extern "C" void kernel_launch(void* const* d_in, const int* in_sizes, int n_in,
                              void* d_out, int out_size, void* d_ws, size_t ws_size,
                              hipStream_t stream) {
    (void)in_sizes; (void)n_in; (void)out_size; (void)ws_size;
    const float* Q  = (const float*)d_in[0];
    const float* Kk = (const float*)d_in[1];
    const float* W1 = (const float*)d_in[2];
    const float* b1 = (const float*)d_in[3];
    const float* a1 = (const float*)d_in[4];
    const float* W2 = (const float*)d_in[5];
    const float* b2 = (const float*)d_in[6];
    const float* a2 = (const float*)d_in[7];
    const float* W3 = (const float*)d_in[8];
    const float* b3 = (const float*)d_in[9];
    const float* a3 = (const float*)d_in[10];
    const float* Wl = (const float*)d_in[11];
    const float* bl = (const float*)d_in[12];
    float* Out = (float*)d_out;

    u16* ws  = (u16*)d_ws;
    u16* W1p = ws;                         // 65536 bf16
    u16* W2p = W1p + 65536;                // 32768
    u16* W3p = W2p + 32768;                //  8192
    u16* A1p = W3p + 8192;                 // 65536
    u16* A2p = A1p + 65536;                // 32768
    u16* A3p = A2p + 32768;                // 16384

    hipLaunchKernelGGL(pack_all, dim3(864), dim3(256), 0, stream,
                       W1, W2, W3, a1, a2, a3, W1p, W2p, W3p, A1p, A2p, A3p);
    hipLaunchKernelGGL(attn_pool_kernel, dim3(BB), dim3(512), 0, stream,
                       Q, Kk, W1p, b1, A1p, W2p, b2, A2p, W3p, b3, A3p, Wl, bl, Out);
}